// Round 2
// baseline (314.636 us; speedup 1.0000x reference)
//
#include <hip/hip_runtime.h>
#include <hip/hip_bf16.h>
#include <cmath>

typedef __bf16 bf16_t;
typedef __bf16 bf16x8 __attribute__((ext_vector_type(8)));
typedef __bf16 bf16x4 __attribute__((ext_vector_type(4)));
typedef float  f32x4  __attribute__((ext_vector_type(4)));

static constexpr int B_  = 2, S_ = 2048, H_ = 1024, I_ = 2048, NST = 16;
static constexpr int ROWS  = B_ * S_;      // 4096
static constexpr int TWO_I = 2 * I_;       // 4096
static constexpr int XPD   = 2 * NST + 1;  // 33
static constexpr int XPDP  = 36;           // padded j-rows

#define AS_G(p) ((const __attribute__((address_space(1))) void*)(p))
#define AS_L(p) ((__attribute__((address_space(3))) void*)(p))

// ---------------- prep kernels ----------------

__global__ __launch_bounds__(256) void cvt_bf16_kernel(
    const float* __restrict__ in, bf16_t* __restrict__ out, int n4)
{
    int i = blockIdx.x * 256 + threadIdx.x;
    if (i < n4) {
        f32x4 v = *(const f32x4*)(in + (size_t)i * 4);
        bf16x4 o;
        o[0] = (bf16_t)v[0]; o[1] = (bf16_t)v[1];
        o[2] = (bf16_t)v[2]; o[3] = (bf16_t)v[3];
        *(bf16x4*)(out + (size_t)i * 4) = o;
    }
}

// in: f32 [R][C] -> out: bf16 [C][R]
__global__ __launch_bounds__(256) void tcvt_kernel(
    const float* __restrict__ in, bf16_t* __restrict__ out, int R, int C)
{
    __shared__ float t[32][33];
    const int tx = threadIdx.x, ty = threadIdx.y;
    const int r0 = blockIdx.y * 32, c0 = blockIdx.x * 32;
    #pragma unroll
    for (int k = 0; k < 4; ++k)
        t[ty + 8 * k][tx] = in[(size_t)(r0 + ty + 8 * k) * C + c0 + tx];
    __syncthreads();
    #pragma unroll
    for (int k = 0; k < 4; ++k)
        out[(size_t)(c0 + ty + 8 * k) * R + r0 + tx] = (bf16_t)t[tx][ty + 8 * k];
}

__device__ __forceinline__ float softplus_f(float x) {
    return x > 15.f ? x : log1pf(__expf(x));
}

__device__ __forceinline__ float dot4(f32x4 a, f32x4 b) {
    return a[0]*b[0] + a[1]*b[1] + a[2]*b[2] + a[3]*b[3];
}

// channel-major transposed weights:
//   WxT [36][2048] (rows 33..35 zero), A2T [16][2048] (pre-scaled by -clip(softplus)*log2e),
//   cwT [4][2048]
__global__ __launch_bounds__(256) void prep_wts(
    const float* __restrict__ A_param, const float* __restrict__ Wx,
    const float* __restrict__ conv_w,
    float* __restrict__ A2T, float* __restrict__ WxT, float* __restrict__ cwT)
{
    int i = blockIdx.x * 256 + threadIdx.x;
    if (i < XPDP * I_) {
        int j = i >> 11, c = i & (I_ - 1);
        WxT[i] = (j < XPD) ? Wx[(size_t)c * XPD + j] : 0.f;
    }
    if (i < NST * I_) {
        int n = i >> 11, c = i & (I_ - 1);
        float sp = softplus_f(A_param[(size_t)c * NST + n]);
        A2T[i] = -fminf(fmaxf(sp, 0.1f), 10.f) * 1.44269504088896340736f;
    }
    if (i < 4 * I_) {
        int j = i >> 11, c = i & (I_ - 1);
        cwT[i] = conv_w[(size_t)c * 4 + j];
    }
}

// ---------------- GEMM: C[M][N] = A[M][K] * Bt[N][K]^T  (bf16 in, f32 out) ----------------

template<int M, int N, int K>
__global__ __launch_bounds__(256)
void gemm_bt(const bf16_t* __restrict__ A, const bf16_t* __restrict__ Bt,
             float* __restrict__ C)
{
    constexpr int BM = 128, BN = 128, BK = 32;
    __shared__ bf16_t lA[BM * BK];
    __shared__ bf16_t lB[BN * BK];

    const int bm   = blockIdx.y * BM;
    const int bn   = blockIdx.x * BN;
    const int tid  = threadIdx.x;
    const int lane = tid & 63;
    const int wave = tid >> 6;
    const int wm   = (wave >> 1) * 64;
    const int wn   = (wave & 1) * 64;

    const int srow  = lane >> 2;
    const int skoff = (lane & 3) * 8;

    const int frow = lane & 15;
    const int fko  = (lane >> 4) * 8;

    f32x4 acc[4][4];
    #pragma unroll
    for (int m = 0; m < 4; ++m)
        #pragma unroll
        for (int n = 0; n < 4; ++n)
            acc[m][n] = (f32x4){0.f, 0.f, 0.f, 0.f};

    for (int k0 = 0; k0 < K; k0 += BK) {
        #pragma unroll
        for (int t = 0; t < 2; ++t) {
            const int c = wave * 2 + t;
            const bf16_t* ga = A  + (size_t)(bm + c * 16 + srow) * K + k0 + skoff;
            const bf16_t* gb = Bt + (size_t)(bn + c * 16 + srow) * K + k0 + skoff;
            __builtin_amdgcn_global_load_lds(AS_G(ga), AS_L(lA + c * 512), 16, 0, 0);
            __builtin_amdgcn_global_load_lds(AS_G(gb), AS_L(lB + c * 512), 16, 0, 0);
        }
        __syncthreads();

        bf16x8 af[4], bfr[4];
        #pragma unroll
        for (int m = 0; m < 4; ++m)
            af[m] = *(const bf16x8*)(lA + (wm + m * 16 + frow) * BK + fko);
        #pragma unroll
        for (int n = 0; n < 4; ++n)
            bfr[n] = *(const bf16x8*)(lB + (wn + n * 16 + frow) * BK + fko);

        #pragma unroll
        for (int m = 0; m < 4; ++m)
            #pragma unroll
            for (int n = 0; n < 4; ++n)
                acc[m][n] = __builtin_amdgcn_mfma_f32_16x16x32_bf16(
                    af[m], bfr[n], acc[m][n], 0, 0, 0);

        __syncthreads();
    }

    const int crow = (lane >> 4) * 4;
    const int ccol = lane & 15;
    #pragma unroll
    for (int m = 0; m < 4; ++m)
        #pragma unroll
        for (int n = 0; n < 4; ++n)
            #pragma unroll
            for (int r = 0; r < 4; ++r)
                C[(size_t)(bm + wm + m * 16 + crow + r) * N
                  + (bn + wn + n * 16 + ccol)] = acc[m][n][r];
}

// ---------------- fused middle (v2): 2 rows per wave, transposed weights ----------------
// grid: ROWS/8 blocks of 256 threads; wave w handles rows (blk*8 + 2w, +1).
// lane owns channels c = g*256 + lane*4 .. +3 for g in 0..7 (all loads coalesced).

__global__ __launch_bounds__(256)
void fused_mid(const float* __restrict__ xz,      // [ROWS][TWO_I]
               const float* __restrict__ cwT,     // [4][I_]
               const float* __restrict__ ln_g,
               const float* __restrict__ ln_b,
               const float* __restrict__ WxT,     // [36][I_]
               const float* __restrict__ A2T,     // [16][I_]
               const float* __restrict__ Dv,      // [I_]
               bf16_t* __restrict__ U)            // [ROWS][I_]
{
    const int lane = threadIdx.x & 63;
    const int wave = threadIdx.x >> 6;
    const int row0 = blockIdx.x * 8 + wave * 2;   // even; pair never crosses seq boundary
    const int s0   = row0 & (S_ - 1);

    __shared__ float xpw[4][2][XPDP];
    __shared__ float bcw[4][2][NST];

    const float* xzr = xz + (size_t)row0 * TWO_I;

    float xc0[32], xc1[32];
    float sm0 = 0.f, sq0 = 0.f, sm1 = 0.f, sq1 = 0.f;

    // ---- conv (causal K=4) + silu + LN partial sums ----
    #pragma unroll
    for (int g = 0; g < 8; ++g) {
        const int c = g * 256 + lane * 4;
        const f32x4 w0 = *(const f32x4*)(cwT + 0 * I_ + c);
        const f32x4 w1 = *(const f32x4*)(cwT + 1 * I_ + c);
        const f32x4 w2 = *(const f32x4*)(cwT + 2 * I_ + c);
        const f32x4 w3 = *(const f32x4*)(cwT + 3 * I_ + c);
        const f32x4 z4 = (f32x4){0.f, 0.f, 0.f, 0.f};
        const f32x4 xv0 = (s0 >= 3) ? *(const f32x4*)(xzr - 3 * TWO_I + c) : z4;
        const f32x4 xv1 = (s0 >= 2) ? *(const f32x4*)(xzr - 2 * TWO_I + c) : z4;
        const f32x4 xv2 = (s0 >= 1) ? *(const f32x4*)(xzr - 1 * TWO_I + c) : z4;
        const f32x4 xv3 = *(const f32x4*)(xzr + c);
        const f32x4 xv4 = *(const f32x4*)(xzr + TWO_I + c);
        const f32x4 a0 = w0 * xv0 + w1 * xv1 + w2 * xv2 + w3 * xv3;
        const f32x4 a1 = w0 * xv1 + w1 * xv2 + w2 * xv3 + w3 * xv4;
        #pragma unroll
        for (int e = 0; e < 4; ++e) {
            const float v0 = a0[e], v1 = a1[e];
            const float t0 = v0 / (1.f + __expf(-v0));
            const float t1 = v1 / (1.f + __expf(-v1));
            xc0[g * 4 + e] = t0; xc1[g * 4 + e] = t1;
            sm0 += t0; sq0 += t0 * t0;
            sm1 += t1; sq1 += t1 * t1;
        }
    }

    #pragma unroll
    for (int off = 32; off; off >>= 1) {
        sm0 += __shfl_xor(sm0, off, 64);
        sq0 += __shfl_xor(sq0, off, 64);
        sm1 += __shfl_xor(sm1, off, 64);
        sq1 += __shfl_xor(sq1, off, 64);
    }
    const float mu0 = sm0 * (1.f / I_), mu1 = sm1 * (1.f / I_);
    const float rs0 = rsqrtf(sq0 * (1.f / I_) - mu0 * mu0 + 1e-5f);
    const float rs1 = rsqrtf(sq1 * (1.f / I_) - mu1 * mu1 + 1e-5f);

    // ---- layernorm in place ----
    #pragma unroll
    for (int g = 0; g < 8; ++g) {
        const int c = g * 256 + lane * 4;
        const f32x4 gg = *(const f32x4*)(ln_g + c);
        const f32x4 bb = *(const f32x4*)(ln_b + c);
        #pragma unroll
        for (int e = 0; e < 4; ++e) {
            xc0[g * 4 + e] = (xc0[g * 4 + e] - mu0) * rs0 * gg[e] + bb[e];
            xc1[g * 4 + e] = (xc1[g * 4 + e] - mu1) * rs1 * gg[e] + bb[e];
        }
    }

    // ---- xproj: 36 outputs in 9 batches of 4; butterfly-reduce in-loop ----
    #pragma unroll 1
    for (int jb = 0; jb < 9; ++jb) {
        float p00 = 0.f, p01 = 0.f, p02 = 0.f, p03 = 0.f;
        float p10 = 0.f, p11 = 0.f, p12 = 0.f, p13 = 0.f;
        const float* wb = WxT + (size_t)(jb * 4) * I_;
        #pragma unroll
        for (int g = 0; g < 8; ++g) {
            const int c = g * 256 + lane * 4;
            const f32x4 wv0 = *(const f32x4*)(wb + 0 * I_ + c);
            const f32x4 wv1 = *(const f32x4*)(wb + 1 * I_ + c);
            const f32x4 wv2 = *(const f32x4*)(wb + 2 * I_ + c);
            const f32x4 wv3 = *(const f32x4*)(wb + 3 * I_ + c);
            const f32x4 x0 = (f32x4){xc0[g*4], xc0[g*4+1], xc0[g*4+2], xc0[g*4+3]};
            const f32x4 x1 = (f32x4){xc1[g*4], xc1[g*4+1], xc1[g*4+2], xc1[g*4+3]};
            p00 += dot4(x0, wv0); p01 += dot4(x0, wv1);
            p02 += dot4(x0, wv2); p03 += dot4(x0, wv3);
            p10 += dot4(x1, wv0); p11 += dot4(x1, wv1);
            p12 += dot4(x1, wv2); p13 += dot4(x1, wv3);
        }
        #pragma unroll
        for (int off = 32; off; off >>= 1) {
            p00 += __shfl_xor(p00, off, 64); p01 += __shfl_xor(p01, off, 64);
            p02 += __shfl_xor(p02, off, 64); p03 += __shfl_xor(p03, off, 64);
            p10 += __shfl_xor(p10, off, 64); p11 += __shfl_xor(p11, off, 64);
            p12 += __shfl_xor(p12, off, 64); p13 += __shfl_xor(p13, off, 64);
        }
        if (lane == 0) {
            xpw[wave][0][jb*4+0] = p00; xpw[wave][0][jb*4+1] = p01;
            xpw[wave][0][jb*4+2] = p02; xpw[wave][0][jb*4+3] = p03;
            xpw[wave][1][jb*4+0] = p10; xpw[wave][1][jb*4+1] = p11;
            xpw[wave][1][jb*4+2] = p12; xpw[wave][1][jb*4+3] = p13;
        }
    }
    __syncthreads();

    const float d0 = fminf(fmaxf(softplus_f(xpw[wave][0][0]), 1e-6f), 10.f);
    const float d1 = fminf(fmaxf(softplus_f(xpw[wave][1][0]), 1e-6f), 10.f);
    if (lane < NST)
        bcw[wave][0][lane] = xpw[wave][0][1 + lane] * xpw[wave][0][1 + NST + lane];
    else if (lane < 2 * NST)
        bcw[wave][1][lane - NST] =
            xpw[wave][1][1 + lane - NST] * xpw[wave][1][1 + NST + lane - NST];
    __syncthreads();

    // ---- SSM pointwise + gate + store ----
    const float* z0 = xzr + I_;
    const float* z1 = xzr + TWO_I + I_;
    bf16_t* u0 = U + (size_t)row0 * I_;
    bf16_t* u1 = u0 + I_;
    #pragma unroll
    for (int g = 0; g < 8; ++g) {
        const int c = g * 256 + lane * 4;
        f32x4 sa0 = (f32x4){0.f, 0.f, 0.f, 0.f};
        f32x4 sa1 = (f32x4){0.f, 0.f, 0.f, 0.f};
        #pragma unroll 1
        for (int n = 0; n < NST; ++n) {
            const f32x4 a4 = *(const f32x4*)(A2T + n * I_ + c);
            const float b0 = bcw[wave][0][n];
            const float b1 = bcw[wave][1][n];
            #pragma unroll
            for (int e = 0; e < 4; ++e) {
                const float e0 = fmaxf(exp2f(d0 * a4[e]), 1e-6f);
                const float e1 = fmaxf(exp2f(d1 * a4[e]), 1e-6f);
                sa0[e] += b0 * e0;
                sa1[e] += b1 * e1;
            }
        }
        const f32x4 dvv = *(const f32x4*)(Dv + c);
        const f32x4 zv0 = *(const f32x4*)(z0 + c);
        const f32x4 zv1 = *(const f32x4*)(z1 + c);
        bf16x4 o0, o1;
        #pragma unroll
        for (int e = 0; e < 4; ++e) {
            const float y0 = xc0[g * 4 + e] * (sa0[e] + dvv[e]);
            const float y1 = xc1[g * 4 + e] * (sa1[e] + dvv[e]);
            const float zz0 = zv0[e], zz1 = zv1[e];
            o0[e] = (bf16_t)(y0 * (zz0 / (1.f + __expf(-zz0))));
            o1[e] = (bf16_t)(y1 * (zz1 / (1.f + __expf(-zz1))));
        }
        *(bf16x4*)(u0 + c) = o0;
        *(bf16x4*)(u1 + c) = o1;
    }
}

// ---------------- launch ----------------

extern "C" void kernel_launch(void* const* d_in, const int* in_sizes, int n_in,
                              void* d_out, int out_size, void* d_ws, size_t ws_size,
                              hipStream_t stream)
{
    const float* x     = (const float*)d_in[0];
    const float* W_in  = (const float*)d_in[1];
    const float* convw = (const float*)d_in[2];
    const float* ln_g  = (const float*)d_in[3];
    const float* ln_b  = (const float*)d_in[4];
    const float* Wx    = (const float*)d_in[5];
    const float* A_p   = (const float*)d_in[6];
    const float* Dv    = (const float*)d_in[7];
    const float* W_out = (const float*)d_in[8];
    float* out = (float*)d_out;

    char* ws = (char*)d_ws;
    bf16_t* Xb  = (bf16_t*)(ws);                               // 8 MiB
    bf16_t* W1t = (bf16_t*)(ws + (size_t)(8u  << 20));         // 8 MiB
    bf16_t* Wot = (bf16_t*)(ws + (size_t)(16u << 20));         // 4 MiB
    float*  A2T = (float*) (ws + (size_t)(20u << 20));         // 128 KiB
    float*  WxT = (float*) (ws + (size_t)(21u << 20));         // 288 KiB
    float*  cwT = (float*) (ws + (size_t)(21u << 20) + (512u << 10)); // 32 KiB
    float*  xz  = (float*) (ws + (size_t)(22u << 20));         // 64 MiB
    bf16_t* U   = (bf16_t*)(ws + (size_t)(86u << 20));         // 16 MiB

    cvt_bf16_kernel<<<(ROWS * H_ / 4 + 255) / 256, 256, 0, stream>>>(x, Xb, ROWS * H_ / 4);
    tcvt_kernel<<<dim3(TWO_I / 32, H_ / 32), dim3(32, 8), 0, stream>>>(W_in, W1t, H_, TWO_I);
    tcvt_kernel<<<dim3(H_ / 32, I_ / 32), dim3(32, 8), 0, stream>>>(W_out, Wot, I_, H_);
    prep_wts<<<(XPDP * I_ + 255) / 256, 256, 0, stream>>>(A_p, Wx, convw, A2T, WxT, cwT);

    gemm_bt<ROWS, TWO_I, H_><<<dim3(TWO_I / 128, ROWS / 128), 256, 0, stream>>>(Xb, W1t, xz);
    fused_mid<<<ROWS / 8, 256, 0, stream>>>(xz, cwT, ln_g, ln_b, WxT, A2T, Dv, U);
    gemm_bt<ROWS, H_, I_><<<dim3(H_ / 128, ROWS / 128), 256, 0, stream>>>(U, Wot, out);
}

// Round 3
// 190.036 us; speedup vs baseline: 1.6557x; 1.6557x over previous
//
#include <hip/hip_runtime.h>
#include <hip/hip_bf16.h>
#include <cmath>

typedef __bf16 bf16_t;
typedef __bf16 bf16x8 __attribute__((ext_vector_type(8)));
typedef __bf16 bf16x4 __attribute__((ext_vector_type(4)));
typedef float  f32x4  __attribute__((ext_vector_type(4)));

static constexpr int B_  = 2, S_ = 2048, H_ = 1024, I_ = 2048, NST = 16;
static constexpr int ROWS  = B_ * S_;      // 4096
static constexpr int TWO_I = 2 * I_;       // 4096
static constexpr int XPD   = 2 * NST + 1;  // 33
static constexpr int XPN   = 64;           // padded xproj cols

#define AS_G(p) ((const __attribute__((address_space(1))) void*)(p))
#define AS_L(p) ((__attribute__((address_space(3))) void*)(p))

// ---------------- prep kernels ----------------

__global__ __launch_bounds__(256) void cvt_bf16_kernel(
    const float* __restrict__ in, bf16_t* __restrict__ out, int n4)
{
    int i = blockIdx.x * 256 + threadIdx.x;
    if (i < n4) {
        f32x4 v = *(const f32x4*)(in + (size_t)i * 4);
        bf16x4 o;
        o[0] = (bf16_t)v[0]; o[1] = (bf16_t)v[1];
        o[2] = (bf16_t)v[2]; o[3] = (bf16_t)v[3];
        *(bf16x4*)(out + (size_t)i * 4) = o;
    }
}

// in: f32 [R][C] -> out: bf16 [C][R]
__global__ __launch_bounds__(256) void tcvt_kernel(
    const float* __restrict__ in, bf16_t* __restrict__ out, int R, int C)
{
    __shared__ float t[32][33];
    const int tx = threadIdx.x, ty = threadIdx.y;
    const int r0 = blockIdx.y * 32, c0 = blockIdx.x * 32;
    #pragma unroll
    for (int k = 0; k < 4; ++k)
        t[ty + 8 * k][tx] = in[(size_t)(r0 + ty + 8 * k) * C + c0 + tx];
    __syncthreads();
    #pragma unroll
    for (int k = 0; k < 4; ++k)
        out[(size_t)(c0 + ty + 8 * k) * R + r0 + tx] = (bf16_t)t[tx][ty + 8 * k];
}

__device__ __forceinline__ float softplus_f(float x) {
    return x > 15.f ? x : log1pf(__expf(x));
}

__device__ __forceinline__ f32x4 b2f(bf16x4 v) {
    return (f32x4){(float)v[0], (float)v[1], (float)v[2], (float)v[3]};
}

// A2T[16][2048] = -clip(softplus(A),0.1,10)*log2e (transposed)
// cwT[4][2048], WxTb bf16 [64][2048] (rows 33..63 zero)
__global__ __launch_bounds__(256) void prep_wts(
    const float* __restrict__ A_param, const float* __restrict__ Wx,
    const float* __restrict__ conv_w,
    float* __restrict__ A2T, float* __restrict__ cwT, bf16_t* __restrict__ WxTb)
{
    int i = blockIdx.x * 256 + threadIdx.x;
    if (i < NST * I_) {
        int n = i >> 11, c = i & (I_ - 1);
        float sp = softplus_f(A_param[(size_t)c * NST + n]);
        A2T[i] = -fminf(fmaxf(sp, 0.1f), 10.f) * 1.44269504088896340736f;
    }
    if (i < 4 * I_) {
        int j = i >> 11, c = i & (I_ - 1);
        cwT[i] = conv_w[(size_t)c * 4 + j];
    }
    if (i < XPN * I_) {
        int j = i >> 11, c = i & (I_ - 1);
        WxTb[i] = (j < XPD) ? (bf16_t)Wx[(size_t)c * XPD + j] : (bf16_t)0.f;
    }
}

// ---------------- GEMM: C[M][N] = A[M][K] * Bt[N][K]^T  (bf16 in, OutT out) ----------------

template<int M, int N, int K, typename OutT>
__global__ __launch_bounds__(256)
void gemm_bt(const bf16_t* __restrict__ A, const bf16_t* __restrict__ Bt,
             OutT* __restrict__ C)
{
    constexpr int BM = 128, BN = 128, BK = 32;
    __shared__ bf16_t lA[BM * BK];
    __shared__ bf16_t lB[BN * BK];

    const int bm   = blockIdx.y * BM;
    const int bn   = blockIdx.x * BN;
    const int tid  = threadIdx.x;
    const int lane = tid & 63;
    const int wave = tid >> 6;
    const int wm   = (wave >> 1) * 64;
    const int wn   = (wave & 1) * 64;

    const int srow  = lane >> 2;
    const int skoff = (lane & 3) * 8;

    const int frow = lane & 15;
    const int fko  = (lane >> 4) * 8;

    f32x4 acc[4][4];
    #pragma unroll
    for (int m = 0; m < 4; ++m)
        #pragma unroll
        for (int n = 0; n < 4; ++n)
            acc[m][n] = (f32x4){0.f, 0.f, 0.f, 0.f};

    for (int k0 = 0; k0 < K; k0 += BK) {
        #pragma unroll
        for (int t = 0; t < 2; ++t) {
            const int c = wave * 2 + t;
            const bf16_t* ga = A  + (size_t)(bm + c * 16 + srow) * K + k0 + skoff;
            const bf16_t* gb = Bt + (size_t)(bn + c * 16 + srow) * K + k0 + skoff;
            __builtin_amdgcn_global_load_lds(AS_G(ga), AS_L(lA + c * 512), 16, 0, 0);
            __builtin_amdgcn_global_load_lds(AS_G(gb), AS_L(lB + c * 512), 16, 0, 0);
        }
        __syncthreads();

        bf16x8 af[4], bfr[4];
        #pragma unroll
        for (int m = 0; m < 4; ++m)
            af[m] = *(const bf16x8*)(lA + (wm + m * 16 + frow) * BK + fko);
        #pragma unroll
        for (int n = 0; n < 4; ++n)
            bfr[n] = *(const bf16x8*)(lB + (wn + n * 16 + frow) * BK + fko);

        #pragma unroll
        for (int m = 0; m < 4; ++m)
            #pragma unroll
            for (int n = 0; n < 4; ++n)
                acc[m][n] = __builtin_amdgcn_mfma_f32_16x16x32_bf16(
                    af[m], bfr[n], acc[m][n], 0, 0, 0);

        __syncthreads();
    }

    const int crow = (lane >> 4) * 4;
    const int ccol = lane & 15;
    #pragma unroll
    for (int m = 0; m < 4; ++m)
        #pragma unroll
        for (int n = 0; n < 4; ++n)
            #pragma unroll
            for (int r = 0; r < 4; ++r)
                C[(size_t)(bm + wm + m * 16 + crow + r) * N
                  + (bn + wn + n * 16 + ccol)] = (OutT)acc[m][n][r];
}

// ---------------- conv + silu + layernorm -> xcn (hi/lo bf16) ----------------
// one row per block; 256 threads x 8 channels

__global__ __launch_bounds__(256)
void conv_ln(const bf16_t* __restrict__ xz,     // [ROWS][TWO_I] bf16
             const float* __restrict__ cwT,     // [4][I_]
             const float* __restrict__ ln_g,
             const float* __restrict__ ln_b,
             bf16_t* __restrict__ Xhi,          // [ROWS][I_]
             bf16_t* __restrict__ Xlo)          // [ROWS][I_]
{
    const int row  = blockIdx.x;
    const int s    = row & (S_ - 1);
    const int tid  = threadIdx.x;
    const int lane = tid & 63;
    const int wave = tid >> 6;
    const bf16_t* xzr = xz + (size_t)row * TWO_I;

    __shared__ float lnr[4][2];

    float xc[8];
    float sm = 0.f, sq = 0.f;

    #pragma unroll
    for (int g = 0; g < 2; ++g) {
        const int c = g * 1024 + tid * 4;
        const f32x4 w0 = *(const f32x4*)(cwT + 0 * I_ + c);
        const f32x4 w1 = *(const f32x4*)(cwT + 1 * I_ + c);
        const f32x4 w2 = *(const f32x4*)(cwT + 2 * I_ + c);
        const f32x4 w3 = *(const f32x4*)(cwT + 3 * I_ + c);
        const f32x4 z4 = (f32x4){0.f, 0.f, 0.f, 0.f};
        const f32x4 xv0 = (s >= 3) ? b2f(*(const bf16x4*)(xzr - 3 * TWO_I + c)) : z4;
        const f32x4 xv1 = (s >= 2) ? b2f(*(const bf16x4*)(xzr - 2 * TWO_I + c)) : z4;
        const f32x4 xv2 = (s >= 1) ? b2f(*(const bf16x4*)(xzr - 1 * TWO_I + c)) : z4;
        const f32x4 xv3 = b2f(*(const bf16x4*)(xzr + c));
        const f32x4 a = w0 * xv0 + w1 * xv1 + w2 * xv2 + w3 * xv3;
        #pragma unroll
        for (int e = 0; e < 4; ++e) {
            const float v = a[e];
            const float t = v / (1.f + __expf(-v));
            xc[g * 4 + e] = t;
            sm += t; sq += t * t;
        }
    }

    #pragma unroll
    for (int off = 32; off; off >>= 1) {
        sm += __shfl_xor(sm, off, 64);
        sq += __shfl_xor(sq, off, 64);
    }
    if (lane == 0) { lnr[wave][0] = sm; lnr[wave][1] = sq; }
    __syncthreads();
    sm = lnr[0][0] + lnr[1][0] + lnr[2][0] + lnr[3][0];
    sq = lnr[0][1] + lnr[1][1] + lnr[2][1] + lnr[3][1];
    const float mu = sm * (1.f / I_);
    const float rs = rsqrtf(sq * (1.f / I_) - mu * mu + 1e-5f);

    #pragma unroll
    for (int g = 0; g < 2; ++g) {
        const int c = g * 1024 + tid * 4;
        const f32x4 gg = *(const f32x4*)(ln_g + c);
        const f32x4 bb = *(const f32x4*)(ln_b + c);
        bf16x4 h4, l4;
        #pragma unroll
        for (int e = 0; e < 4; ++e) {
            const float xn = (xc[g * 4 + e] - mu) * rs * gg[e] + bb[e];
            const bf16_t hi = (bf16_t)xn;
            h4[e] = hi;
            l4[e] = (bf16_t)(xn - (float)hi);
        }
        *(bf16x4*)(Xhi + (size_t)row * I_ + c) = h4;
        *(bf16x4*)(Xlo + (size_t)row * I_ + c) = l4;
    }
}

// ---------------- xproj GEMM: xp_part[ks][ROWS][64] = (Xhi+Xlo) @ WxTb^T ----------------
// BM=128, BN=64, split-K=4; accumulates hi-pass then lo-pass.

__global__ __launch_bounds__(256)
void xproj_gemm(const bf16_t* __restrict__ Ahi, const bf16_t* __restrict__ Alo,
                const bf16_t* __restrict__ Wb, float* __restrict__ xp_part)
{
    constexpr int BM = 128, BK = 32, KS = 512;
    __shared__ bf16_t lA[BM * BK];
    __shared__ bf16_t lB[XPN * BK];

    const int bm   = blockIdx.x * BM;
    const int ks   = blockIdx.y;
    const int tid  = threadIdx.x;
    const int lane = tid & 63;
    const int wave = tid >> 6;
    const int wm   = (wave >> 1) * 64;
    const int wn   = (wave & 1) * 32;

    const int srow  = lane >> 2;
    const int skoff = (lane & 3) * 8;
    const int frow  = lane & 15;
    const int fko   = (lane >> 4) * 8;

    f32x4 acc[4][2];
    #pragma unroll
    for (int m = 0; m < 4; ++m)
        #pragma unroll
        for (int n = 0; n < 2; ++n)
            acc[m][n] = (f32x4){0.f, 0.f, 0.f, 0.f};

    #pragma unroll 1
    for (int pass = 0; pass < 2; ++pass) {
        const bf16_t* A = pass ? Alo : Ahi;
        for (int k0 = ks * KS; k0 < ks * KS + KS; k0 += BK) {
            #pragma unroll
            for (int t = 0; t < 2; ++t) {
                const int c = wave * 2 + t;
                const bf16_t* ga = A + (size_t)(bm + c * 16 + srow) * I_ + k0 + skoff;
                __builtin_amdgcn_global_load_lds(AS_G(ga), AS_L(lA + c * 512), 16, 0, 0);
            }
            const bf16_t* gb = Wb + (size_t)(wave * 16 + srow) * I_ + k0 + skoff;
            __builtin_amdgcn_global_load_lds(AS_G(gb), AS_L(lB + wave * 512), 16, 0, 0);
            __syncthreads();

            bf16x8 af[4], bf2[2];
            #pragma unroll
            for (int m = 0; m < 4; ++m)
                af[m] = *(const bf16x8*)(lA + (wm + m * 16 + frow) * BK + fko);
            #pragma unroll
            for (int n = 0; n < 2; ++n)
                bf2[n] = *(const bf16x8*)(lB + (wn + n * 16 + frow) * BK + fko);

            #pragma unroll
            for (int m = 0; m < 4; ++m)
                #pragma unroll
                for (int n = 0; n < 2; ++n)
                    acc[m][n] = __builtin_amdgcn_mfma_f32_16x16x32_bf16(
                        af[m], bf2[n], acc[m][n], 0, 0, 0);

            __syncthreads();
        }
    }

    float* out = xp_part + ((size_t)ks * ROWS + bm) * XPN;
    const int crow = (lane >> 4) * 4;
    const int ccol = lane & 15;
    #pragma unroll
    for (int m = 0; m < 4; ++m)
        #pragma unroll
        for (int n = 0; n < 2; ++n)
            #pragma unroll
            for (int r = 0; r < 4; ++r)
                out[(size_t)(wm + m * 16 + crow + r) * XPN
                    + (wn + n * 16 + ccol)] = acc[m][n][r];
}

// ---------------- SSM pointwise + gate -> U (bf16); 2 rows per block ----------------

__global__ __launch_bounds__(256)
void ssm_gate(const bf16_t* __restrict__ xz,      // [ROWS][TWO_I] bf16 (z half used)
              const bf16_t* __restrict__ Xhi,
              const bf16_t* __restrict__ Xlo,
              const float* __restrict__ xp_part,  // [4][ROWS][64]
              const float* __restrict__ A2T,      // [16][I_]
              const float* __restrict__ Dv,       // [I_]
              bf16_t* __restrict__ U)             // [ROWS][I_]
{
    const int row0 = blockIdx.x * 2;
    const int tid  = threadIdx.x;

    __shared__ float xps[2][XPD];
    __shared__ float bcs[2][NST];

    if (tid < XPD) {
        float s = 0.f;
        #pragma unroll
        for (int ks = 0; ks < 4; ++ks)
            s += xp_part[((size_t)ks * ROWS + row0) * XPN + tid];
        xps[0][tid] = s;
    } else if (tid >= 64 && tid < 64 + XPD) {
        const int j = tid - 64;
        float s = 0.f;
        #pragma unroll
        for (int ks = 0; ks < 4; ++ks)
            s += xp_part[((size_t)ks * ROWS + row0 + 1) * XPN + j];
        xps[1][j] = s;
    }
    __syncthreads();
    if (tid < NST)
        bcs[0][tid] = xps[0][1 + tid] * xps[0][1 + NST + tid];
    else if (tid >= 64 && tid < 64 + NST) {
        const int n = tid - 64;
        bcs[1][n] = xps[1][1 + n] * xps[1][1 + NST + n];
    }
    __syncthreads();

    const float d0 = fminf(fmaxf(softplus_f(xps[0][0]), 1e-6f), 10.f);
    const float d1 = fminf(fmaxf(softplus_f(xps[1][0]), 1e-6f), 10.f);

    const bf16_t* z0 = xz + (size_t)row0 * TWO_I + I_;
    const bf16_t* z1 = z0 + TWO_I;
    bf16_t* u0 = U + (size_t)row0 * I_;
    bf16_t* u1 = u0 + I_;

    #pragma unroll
    for (int g = 0; g < 2; ++g) {
        const int c = g * 1024 + tid * 4;
        f32x4 sa0 = (f32x4){0.f, 0.f, 0.f, 0.f};
        f32x4 sa1 = (f32x4){0.f, 0.f, 0.f, 0.f};
        #pragma unroll 4
        for (int n = 0; n < NST; ++n) {
            const f32x4 a4 = *(const f32x4*)(A2T + n * I_ + c);
            const float b0 = bcs[0][n];
            const float b1 = bcs[1][n];
            #pragma unroll
            for (int e = 0; e < 4; ++e) {
                sa0[e] += b0 * fmaxf(exp2f(d0 * a4[e]), 1e-6f);
                sa1[e] += b1 * fmaxf(exp2f(d1 * a4[e]), 1e-6f);
            }
        }
        const f32x4 dvv = *(const f32x4*)(Dv + c);
        const f32x4 xn0 = b2f(*(const bf16x4*)(Xhi + (size_t)row0 * I_ + c))
                        + b2f(*(const bf16x4*)(Xlo + (size_t)row0 * I_ + c));
        const f32x4 xn1 = b2f(*(const bf16x4*)(Xhi + (size_t)(row0 + 1) * I_ + c))
                        + b2f(*(const bf16x4*)(Xlo + (size_t)(row0 + 1) * I_ + c));
        const f32x4 zv0 = b2f(*(const bf16x4*)(z0 + c));
        const f32x4 zv1 = b2f(*(const bf16x4*)(z1 + c));
        bf16x4 o0, o1;
        #pragma unroll
        for (int e = 0; e < 4; ++e) {
            const float y0 = xn0[e] * (sa0[e] + dvv[e]);
            const float y1 = xn1[e] * (sa1[e] + dvv[e]);
            const float zz0 = zv0[e], zz1 = zv1[e];
            o0[e] = (bf16_t)(y0 * (zz0 / (1.f + __expf(-zz0))));
            o1[e] = (bf16_t)(y1 * (zz1 / (1.f + __expf(-zz1))));
        }
        *(bf16x4*)(u0 + c) = o0;
        *(bf16x4*)(u1 + c) = o1;
    }
}

// ---------------- launch ----------------

extern "C" void kernel_launch(void* const* d_in, const int* in_sizes, int n_in,
                              void* d_out, int out_size, void* d_ws, size_t ws_size,
                              hipStream_t stream)
{
    const float* x     = (const float*)d_in[0];
    const float* W_in  = (const float*)d_in[1];
    const float* convw = (const float*)d_in[2];
    const float* ln_g  = (const float*)d_in[3];
    const float* ln_b  = (const float*)d_in[4];
    const float* Wx    = (const float*)d_in[5];
    const float* A_p   = (const float*)d_in[6];
    const float* Dv    = (const float*)d_in[7];
    const float* W_out = (const float*)d_in[8];
    float* out = (float*)d_out;

    char* ws = (char*)d_ws;
    bf16_t* Xb   = (bf16_t*)(ws);                                // 8 MiB (dead after GEMM1)
    bf16_t* W1t  = (bf16_t*)(ws + (size_t)(8u  << 20));          // 8 MiB (dead after GEMM1)
    bf16_t* Wot  = (bf16_t*)(ws + (size_t)(16u << 20));          // 4 MiB
    float*  A2T  = (float*) (ws + (size_t)(20u << 20));          // 128 KiB
    float*  cwT  = (float*) (ws + (size_t)(20u << 20) + (128u << 10)); // 32 KiB
    bf16_t* WxTb = (bf16_t*)(ws + (size_t)(20u << 20) + (256u << 10)); // 256 KiB
    bf16_t* XZb  = (bf16_t*)(ws + (size_t)(22u << 20));          // 32 MiB [4096][4096]
    bf16_t* U    = (bf16_t*)(ws + (size_t)(54u << 20));          // 16 MiB
    bf16_t* Xhi  = (bf16_t*)(ws);                                // 16 MiB (reuses Xb+W1t)
    bf16_t* Xlo  = (bf16_t*)(ws + (size_t)(70u << 20));          // 16 MiB
    float*  xp4  = (float*) (ws + (size_t)(86u << 20));          // 4 MiB [4][4096][64]

    cvt_bf16_kernel<<<(ROWS * H_ / 4 + 255) / 256, 256, 0, stream>>>(x, Xb, ROWS * H_ / 4);
    tcvt_kernel<<<dim3(TWO_I / 32, H_ / 32), dim3(32, 8), 0, stream>>>(W_in, W1t, H_, TWO_I);
    tcvt_kernel<<<dim3(H_ / 32, I_ / 32), dim3(32, 8), 0, stream>>>(W_out, Wot, I_, H_);
    prep_wts<<<(XPN * I_ + 255) / 256, 256, 0, stream>>>(A_p, Wx, convw, A2T, cwT, WxTb);

    gemm_bt<ROWS, TWO_I, H_, bf16_t>
        <<<dim3(TWO_I / 128, ROWS / 128), 256, 0, stream>>>(Xb, W1t, XZb);
    conv_ln<<<ROWS, 256, 0, stream>>>(XZb, cwT, ln_g, ln_b, Xhi, Xlo);
    xproj_gemm<<<dim3(ROWS / 128, 4), 256, 0, stream>>>(Xhi, Xlo, WxTb, xp4);
    ssm_gate<<<ROWS / 2, 256, 0, stream>>>(XZb, Xhi, Xlo, xp4, A2T, Dv, U);
    gemm_bt<ROWS, H_, I_, float>
        <<<dim3(H_ / 128, ROWS / 128), 256, 0, stream>>>(U, Wot, out);
}